// Round 11
// baseline (170.476 us; speedup 1.0000x reference)
//
#include <hip/hip_runtime.h>
#include <hip/hip_bf16.h>

#define GN 4096
#define GF 512
#define GH 8
#define GC 128
#define CAP 256          // max stored neighbors/row; deg ~ Bin(4096,0.01) = 41±6.4
#define LCAP 128         // attn LDS cap; P(deg>128) < 1e-20 for this graph
#define XS 72            // padded LDS row stride (u16): 144 B, 16B-aligned

typedef __hip_bfloat16 bf16;
typedef unsigned short u16;
typedef unsigned int u32;
typedef __attribute__((ext_vector_type(8))) short bf16x8;   // 8 bf16 = 4 VGPRs
typedef __attribute__((ext_vector_type(4))) float f32x4;

static __device__ inline u16 f2u16(float x) {
    union { bf16 b; u16 u; } cv;
    cv.b = __float2bfloat16(x);
    return cv.u;
}

static __device__ inline float bf2f(short s) {
    return __uint_as_float((u32)(u16)s << 16);
}

// ---------------------------------------------------------------------------
// Kernel 1 (fused prep + csr — r9): REVERTED to the r7 serial structure
// (r8's feats+csr fusion thrashed L2: fused FETCH 12->45 MB, 49.5 us).
// NEW vs r7: (1) block ranges reordered — csr FIRST [0,4096), X convert
// [4096,5120), W transpose [5120,5184) — so Xb/WT are written at the TAIL
// and sit L2-warm for the feats kernel (previously the 64 MB A stream
// drained last and evicted them). (2) A loads are NON-TEMPORAL (read-once
// stream; don't claim L2 replacement priority).
// ---------------------------------------------------------------------------
__global__ __launch_bounds__(256) void prep_csr_kernel(
    const float* __restrict__ A, const float* __restrict__ X,
    const float* __restrict__ W, int* __restrict__ deg,
    u16* __restrict__ lists, u16* __restrict__ Xb, u16* __restrict__ WT)
{
    __shared__ u16 sT[16][520];            // 16.6 KB; csr aliases sT[0..1] as cnt
    int tid = threadIdx.x;
    int b   = blockIdx.x;

    if (b < GN) {
        // ---- csr: row i (r7 body: 4 loads in flight, single atomic) ----
        int i    = b;
        int lane = tid & 63;
        int* cnt = (int*)&sT[0][0];
        if (tid == 0) *cnt = 0;
        __syncthreads();

        u16* row = lists + (size_t)i * CAP;
        const f32x4* Arow = (const f32x4*)(A + (size_t)i * GN);
        unsigned long long ltmask = (lane == 63) ? ~0ull >> 1
                                                 : (1ull << lane) - 1;
        f32x4 av[4];                       // 4 independent nt loads in flight
#pragma unroll
        for (int it = 0; it < 4; ++it)
            av[it] = __builtin_nontemporal_load(&Arow[it * 256 + tid]);

#pragma unroll
        for (int it = 0; it < 4; ++it) {
            f32x4 a = av[it];
            int j = (it * 256 + tid) * 4;
            bool f0 = a.x > 0.5f, f1 = a.y > 0.5f;
            bool f2 = a.z > 0.5f, f3 = a.w > 0.5f;
            unsigned long long m0 = __ballot(f0);
            unsigned long long m1 = __ballot(f1);
            unsigned long long m2 = __ballot(f2);
            unsigned long long m3 = __ballot(f3);
            int c0 = __popcll(m0), c1 = __popcll(m1), c2 = __popcll(m2);
            int tot = c0 + c1 + c2 + __popcll(m3);
            int base = 0;
            if (lane == 0 && tot) base = atomicAdd(cnt, tot);
            base = __shfl(base, 0);
            if (tot) {
                if (f0) {
                    int s = base + __popcll(m0 & ltmask);
                    if (s < CAP) row[s] = (u16)j;
                }
                if (f1) {
                    int s = base + c0 + __popcll(m1 & ltmask);
                    if (s < CAP) row[s] = (u16)(j + 1);
                }
                if (f2) {
                    int s = base + c0 + c1 + __popcll(m2 & ltmask);
                    if (s < CAP) row[s] = (u16)(j + 2);
                }
                if (f3) {
                    int s = base + c0 + c1 + c2 + __popcll(m3 & ltmask);
                    if (s < CAP) row[s] = (u16)(j + 3);
                }
            }
        }
        __syncthreads();
        if (tid == 0) deg[i] = *cnt < CAP ? *cnt : CAP;
        return;
    }
    if (b < GN + 1024) {
        // ---- X fp32 -> bf16 (tail: leaves Xb L2-warm for feats) ----
        int xb = b - GN;
        size_t idx = ((size_t)xb * 256 + tid) * 8;
        float4 v0 = *(const float4*)(X + idx);
        float4 v1 = *(const float4*)(X + idx + 4);
        u16 o[8] = {f2u16(v0.x), f2u16(v0.y), f2u16(v0.z), f2u16(v0.w),
                    f2u16(v1.x), f2u16(v1.y), f2u16(v1.z), f2u16(v1.w)};
        *(bf16x8*)(Xb + idx) = *(bf16x8*)o;
        return;
    }
    // ---- W transpose to WT[h][n][k] (tail) ----
    int wb = b - GN - 1024;                // 0..63
    int h  = wb >> 3;
    int s16 = (wb & 7) * 16;
    const float* Wh = W + (size_t)h * GF * GC;
    for (int pass = 0; pass < 8; ++pass) {
        int k  = pass * 64 + (tid >> 2);
        int n4 = tid & 3;
        float4 v = *(const float4*)&Wh[(size_t)k * GC + s16 + n4 * 4];
        sT[n4 * 4 + 0][k] = f2u16(v.x);
        sT[n4 * 4 + 1][k] = f2u16(v.y);
        sT[n4 * 4 + 2][k] = f2u16(v.z);
        sT[n4 * 4 + 3][k] = f2u16(v.w);
    }
    __syncthreads();
    int n = tid >> 4, seg = tid & 15;
    u16* dst = WT + ((size_t)h * GC + s16 + n) * GF + seg * 32;
#pragma unroll
    for (int s = 0; s < 4; ++s)
        *(bf16x8*)(dst + s * 8) = *(const bf16x8*)&sT[n][seg * 32 + s * 8];
}

// ---------------------------------------------------------------------------
// Kernel 2 (MFMA feats — r4 body, unchanged): feats = Xb @ WT^T, BM=64
// BN=128 BK=64. Output layout [hp][N][2*C] (2 MB head-pair slabs). Direct
// bf16 epilogue stores.
// ---------------------------------------------------------------------------
__global__ __launch_bounds__(256) void feats_kernel(
    const u16* __restrict__ Xb, const u16* __restrict__ WT,
    const float* __restrict__ a_self, const float* __restrict__ a_neigh,
    u16* __restrict__ featsb, float* __restrict__ ssT,
    float* __restrict__ snT)
{
    __shared__ u16 sX[64 * XS];    //  9.2 KB
    __shared__ u16 sW[128 * XS];   // 18.4 KB

    int h   = blockIdx.x >> 6;
    int n0  = (blockIdx.x & 63) << 6;
    int tid = threadIdx.x;
    int lane = tid & 63, wv = tid >> 6;
    int lm = lane & 15, q = lane >> 4;

    const u16* Xp = Xb + (size_t)n0 * GF;
    const u16* Wp = WT + (size_t)h * GC * GF;

    uint4 xr[2], wr[4];

#define ISSUE_TILE(K0)                                                        \
    {                                                                         \
        _Pragma("unroll")                                                     \
        for (int it = 0; it < 2; ++it) {                                      \
            int idx = it * 256 + tid, row = idx >> 3, c = idx & 7;            \
            xr[it] = *(const uint4*)&Xp[(size_t)row * GF + (K0) + c * 8];     \
        }                                                                     \
        _Pragma("unroll")                                                     \
        for (int it = 0; it < 4; ++it) {                                      \
            int idx = it * 256 + tid, row = idx >> 3, c = idx & 7;            \
            wr[it] = *(const uint4*)&Wp[(size_t)row * GF + (K0) + c * 8];     \
        }                                                                     \
    }

#define STORE_TILE()                                                          \
    {                                                                         \
        _Pragma("unroll")                                                     \
        for (int it = 0; it < 2; ++it) {                                      \
            int idx = it * 256 + tid, row = idx >> 3, c = idx & 7;            \
            *(uint4*)&sX[row * XS + c * 8] = xr[it];                          \
        }                                                                     \
        _Pragma("unroll")                                                     \
        for (int it = 0; it < 4; ++it) {                                      \
            int idx = it * 256 + tid, row = idx >> 3, c = idx & 7;            \
            *(uint4*)&sW[row * XS + c * 8] = wr[it];                          \
        }                                                                     \
    }

    f32x4 acc[8];
#pragma unroll
    for (int nt = 0; nt < 8; ++nt) acc[nt] = (f32x4){0.f, 0.f, 0.f, 0.f};

    ISSUE_TILE(0)
    STORE_TILE()

    for (int k0 = 0; k0 < GF; k0 += 64) {
        __syncthreads();                       // tile k0 visible
        if (k0 + 64 < GF) ISSUE_TILE(k0 + 64)  // next tile in flight

#pragma unroll
        for (int ks = 0; ks < 64; ks += 32) {
            bf16x8 af = *(const bf16x8*)&sX[(wv * 16 + lm) * XS + ks + q * 8];
            bf16x8 bfr[8];
#pragma unroll
            for (int nt = 0; nt < 8; ++nt)
                bfr[nt] = *(const bf16x8*)&sW[(nt * 16 + lm) * XS + ks + q * 8];
#pragma unroll
            for (int nt = 0; nt < 8; ++nt)
                acc[nt] = __builtin_amdgcn_mfma_f32_16x16x32_bf16(
                    af, bfr[nt], acc[nt], 0, 0, 0);
        }
        __syncthreads();                       // readers done
        if (k0 + 64 < GF) STORE_TILE()
    }
#undef ISSUE_TILE
#undef STORE_TILE

    // epilogue: direct bf16 stores into [hp][N][2C] + fused score vectors
    float aS[8], aN[8];
#pragma unroll
    for (int nt = 0; nt < 8; ++nt) {
        aS[nt] = a_self[h * GC + nt * 16 + lm];
        aN[nt] = a_neigh[h * GC + nt * 16 + lm];
    }
    float vs[4] = {0.f, 0.f, 0.f, 0.f};
    float vn[4] = {0.f, 0.f, 0.f, 0.f};
    int rbase = n0 + wv * 16 + q * 4;          // D row = quad*4+reg (m89)
    u16* fB = featsb + (size_t)(h >> 1) * GN * 256 + (h & 1) * 128;
#pragma unroll
    for (int nt = 0; nt < 8; ++nt) {
        f32x4 v = acc[nt];
        int col = nt * 16 + lm;                // D col = lane&15
#pragma unroll
        for (int r = 0; r < 4; ++r) {
            fB[(size_t)(rbase + r) * 256 + col] = f2u16(v[r]);
            vs[r] += v[r] * aS[nt];
            vn[r] += v[r] * aN[nt];
        }
    }
#pragma unroll
    for (int r = 0; r < 4; ++r) {
        for (int off = 1; off < 16; off <<= 1) {
            vs[r] += __shfl_xor(vs[r], off);
            vn[r] += __shfl_xor(vn[r], off);
        }
        if (lm == 0) {
            ssT[(rbase + r) * GH + h] = vs[r];
            snT[(rbase + r) * GH + h] = vn[r];
        }
    }
}

// ---------------------------------------------------------------------------
// Kernel 3 (attn — r7 body, unchanged): XCD-affine slab pinning + register
// softmax (single LDS write) + parity-split dwordx4 gather, 4-pair unroll.
// ---------------------------------------------------------------------------
__global__ __launch_bounds__(256) void attn_kernel(
    const int* __restrict__ deg, const u16* __restrict__ lists,
    const float* __restrict__ bias, const u16* __restrict__ featsb,
    const float* __restrict__ ssT, const float* __restrict__ snT,
    float* __restrict__ out)
{
    int tid  = threadIdx.x;
    int wv   = tid >> 6, lane = tid & 63;
    int bid  = blockIdx.x;
    int r8   = bid & 7;                    // presumed XCD id
    int hp   = r8 >> 1;                    // slab pinned to XCD pair
    int i    = (bid >> 3) * 8 + (r8 & 1) * 4 + wv;   // 0..4095, bijective

    __shared__ float4 pjbuf[4][LCAP];      // 8 KB: (p0, p1, j, pad) per wave
    float4* pj = pjbuf[wv];

    int M = deg[i];
    M = M < LCAP ? M : LCAP;
    const u16* row = lists + (size_t)i * CAP;

    float2 ssv = *(const float2*)&ssT[(size_t)i * GH + hp * 2];

    // single pass: scores for this lane's <=2 neighbors stay in registers
    int ka = lane, kb = lane + 64;
    int ja = 0, jb = 0;
    float e0a = -1e30f, e1a = -1e30f, e0b = -1e30f, e1b = -1e30f;
    if (ka < M) {
        ja = row[ka];
        float2 sn = *(const float2*)&snT[(size_t)ja * GH + hp * 2];
        e0a = ssv.x + sn.x; e0a = e0a > 0.f ? e0a : 0.2f * e0a;
        e1a = ssv.y + sn.y; e1a = e1a > 0.f ? e1a : 0.2f * e1a;
    }
    if (kb < M) {
        jb = row[kb];
        float2 sn = *(const float2*)&snT[(size_t)jb * GH + hp * 2];
        e0b = ssv.x + sn.x; e0b = e0b > 0.f ? e0b : 0.2f * e0b;
        e1b = ssv.y + sn.y; e1b = e1b > 0.f ? e1b : 0.2f * e1b;
    }
    float m0 = fmaxf(e0a, e0b), m1 = fmaxf(e1a, e1b);
#pragma unroll
    for (int off = 32; off > 0; off >>= 1) {
        m0 = fmaxf(m0, __shfl_xor(m0, off));
        m1 = fmaxf(m1, __shfl_xor(m1, off));
    }

    // exp from registers, one LDS write, sums
    float s0 = 0.f, s1 = 0.f;
    if (ka < M) {
        float p0 = __expf(e0a - m0), p1 = __expf(e1a - m1);
        pj[ka] = make_float4(p0, p1, __int_as_float(ja), 0.f);
        s0 += p0; s1 += p1;
    }
    if (kb < M) {
        float p0 = __expf(e0b - m0), p1 = __expf(e1b - m1);
        pj[kb] = make_float4(p0, p1, __int_as_float(jb), 0.f);
        s0 += p0; s1 += p1;
    }
#pragma unroll
    for (int off = 32; off > 0; off >>= 1) {
        s0 += __shfl_xor(s0, off);
        s1 += __shfl_xor(s1, off);
    }

    int par = lane >> 5;                   // neighbor-parity of this lane
    int cl  = lane & 31;                   // 16 B channel block 0..31
    float inv = (cl < 16) ? 1.f / s0 : 1.f / s1;

    // gather: lane reads 16 B (8 channels) of neighbor (k + par)'s 512 B row
    const u16* fb = featsb + (size_t)hp * GN * 256 + cl * 8;
    float a0 = 0.f, a1 = 0.f, a2 = 0.f, a3 = 0.f;
    float a4 = 0.f, a5 = 0.f, a6 = 0.f, a7 = 0.f;

#define ACCUM(Q, WW)                                                          \
    {                                                                         \
        a0 += (WW) * bf2f((Q)[0]); a1 += (WW) * bf2f((Q)[1]);                 \
        a2 += (WW) * bf2f((Q)[2]); a3 += (WW) * bf2f((Q)[3]);                 \
        a4 += (WW) * bf2f((Q)[4]); a5 += (WW) * bf2f((Q)[5]);                 \
        a6 += (WW) * bf2f((Q)[6]); a7 += (WW) * bf2f((Q)[7]);                 \
    }

    int k = 0;
    for (; k + 8 <= M; k += 8) {           // 4 pairs = 4 loads in flight
        float4 v0 = pj[k + par];           // 2-way broadcast (free)
        float4 v1 = pj[k + 2 + par];
        float4 v2 = pj[k + 4 + par];
        float4 v3 = pj[k + 6 + par];
        int j0 = __float_as_int(v0.z), j1 = __float_as_int(v1.z);
        int j2 = __float_as_int(v2.z), j3 = __float_as_int(v3.z);
        bf16x8 q0 = *(const bf16x8*)(fb + (size_t)j0 * 256);
        bf16x8 q1 = *(const bf16x8*)(fb + (size_t)j1 * 256);
        bf16x8 q2 = *(const bf16x8*)(fb + (size_t)j2 * 256);
        bf16x8 q3 = *(const bf16x8*)(fb + (size_t)j3 * 256);
        float w0 = (cl < 16) ? v0.x : v0.y;
        float w1 = (cl < 16) ? v1.x : v1.y;
        float w2 = (cl < 16) ? v2.x : v2.y;
        float w3 = (cl < 16) ? v3.x : v3.y;
        ACCUM(q0, w0)
        ACCUM(q1, w1)
        ACCUM(q2, w2)
        ACCUM(q3, w3)
    }
    if (k + 4 <= M) {
        float4 v0 = pj[k + par], v1 = pj[k + 2 + par];
        int j0 = __float_as_int(v0.z), j1 = __float_as_int(v1.z);
        bf16x8 q0 = *(const bf16x8*)(fb + (size_t)j0 * 256);
        bf16x8 q1 = *(const bf16x8*)(fb + (size_t)j1 * 256);
        float w0 = (cl < 16) ? v0.x : v0.y;
        float w1 = (cl < 16) ? v1.x : v1.y;
        ACCUM(q0, w0)
        ACCUM(q1, w1)
        k += 4;
    }
    if (k + 2 <= M) {
        float4 v0 = pj[k + par];
        int j0 = __float_as_int(v0.z);
        bf16x8 q0 = *(const bf16x8*)(fb + (size_t)j0 * 256);
        float w0 = (cl < 16) ? v0.x : v0.y;
        ACCUM(q0, w0)
        k += 2;
    }
    if (k < M) {                           // single tail: par==1 lanes idle
        float4 v0 = pj[k];
        int j0 = __float_as_int(v0.z);
        bf16x8 q0 = *(const bf16x8*)(fb + (size_t)j0 * 256);
        float w0 = (cl < 16) ? v0.x : v0.y;
        if (par) w0 = 0.f;
        ACCUM(q0, w0)
    }
#undef ACCUM

    // merge parity partial sums (lane l <-> l+32 hold same channels)
    a0 += __shfl_xor(a0, 32); a1 += __shfl_xor(a1, 32);
    a2 += __shfl_xor(a2, 32); a3 += __shfl_xor(a3, 32);
    a4 += __shfl_xor(a4, 32); a5 += __shfl_xor(a5, 32);
    a6 += __shfl_xor(a6, 32); a7 += __shfl_xor(a7, 32);

    if (par == 0) {
        int co = hp * 256 + cl * 8;        // channel offset in [H*C]
        float4 b0 = *(const float4*)&bias[co];
        float4 b1 = *(const float4*)&bias[co + 4];
        float* op = out + (size_t)i * (GH * GC) + co;
        float4 o0, o1;
        o0.x = fmaxf(a0 * inv + b0.x, 0.f);
        o0.y = fmaxf(a1 * inv + b0.y, 0.f);
        o0.z = fmaxf(a2 * inv + b0.z, 0.f);
        o0.w = fmaxf(a3 * inv + b0.w, 0.f);
        o1.x = fmaxf(a4 * inv + b1.x, 0.f);
        o1.y = fmaxf(a5 * inv + b1.y, 0.f);
        o1.z = fmaxf(a6 * inv + b1.z, 0.f);
        o1.w = fmaxf(a7 * inv + b1.w, 0.f);
        *(float4*)op = o0;
        *(float4*)(op + 4) = o1;
    }
}

// ---------------------------------------------------------------------------
extern "C" void kernel_launch(void* const* d_in, const int* in_sizes, int n_in,
                              void* d_out, int out_size, void* d_ws, size_t ws_size,
                              hipStream_t stream)
{
    const float* X       = (const float*)d_in[0];
    const float* A       = (const float*)d_in[1];
    const float* W       = (const float*)d_in[2];
    const float* a_self  = (const float*)d_in[3];
    const float* a_neigh = (const float*)d_in[4];
    const float* bias    = (const float*)d_in[5];
    float* out = (float*)d_out;

    // ws layout: featsb bf16 [4][N][2C] | ssT f32 [N][H] | snT f32 [N][H]
    //            | deg i32 [N] | lists u16 [N*CAP] | Xb u16 [N*F] | WT u16 [H*C*F]
    u16*   featsb = (u16*)d_ws;
    float* ssT    = (float*)(featsb + (size_t)GH * GN * GC);
    float* snT    = ssT + (size_t)GH * GN;
    int*   deg    = (int*)(snT + (size_t)GH * GN);
    u16*   lists  = (u16*)(deg + GN);
    u16*   Xb     = lists + (size_t)GN * CAP;
    u16*   WT     = Xb + (size_t)GN * GF;

    prep_csr_kernel<<<GN + 1088, 256, 0, stream>>>(A, X, W, deg, lists, Xb, WT);
    feats_kernel<<<GH * 64, 256, 0, stream>>>(Xb, WT, a_self, a_neigh,
                                              featsb, ssT, snT);
    attn_kernel<<<GH * GN / 8, 256, 0, stream>>>(deg, lists, bias, featsb,
                                                 ssT, snT, out);
}

// Round 12
// 164.835 us; speedup vs baseline: 1.0342x; 1.0342x over previous
//
#include <hip/hip_runtime.h>
#include <hip/hip_bf16.h>

#define GN 4096
#define GF 512
#define GH 8
#define GC 128
#define CAP 256          // max stored neighbors/row; deg ~ Bin(4096,0.01) = 41±6.4
#define LCAP 128         // attn LDS cap; P(deg>128) < 1e-20 for this graph
#define XS 72            // padded LDS row stride (u16): 144 B, 16B-aligned

typedef __hip_bfloat16 bf16;
typedef unsigned short u16;
typedef unsigned int u32;
typedef __attribute__((ext_vector_type(8))) short bf16x8;   // 8 bf16 = 4 VGPRs
typedef __attribute__((ext_vector_type(4))) float f32x4;

static __device__ inline u16 f2u16(float x) {
    union { bf16 b; u16 u; } cv;
    cv.b = __float2bfloat16(x);
    return cv.u;
}

static __device__ inline float bf2f(short s) {
    return __uint_as_float((u32)(u16)s << 16);
}

// ---------------------------------------------------------------------------
// Kernel 1 (fused prep + csr — r7 MEASURED BEST, restored): heterogeneous
// block ranges. [0,1024): X fp32->bf16. [1024,1088): W transpose.
// [1088,5184): csr — 4 A-chunk loads hoisted (4 dwordx4 in flight), then 4
// ballot groups + ONE combined atomicAdd per iteration. This X/W-first
// ordering is a measured local optimum: csr-first (r9) cost +6.7 us, and
// feats+csr fusion (r8) thrashed L2 (+3 us). Plain cached A loads — nt
// loads were part of the r9 regression.
// ---------------------------------------------------------------------------
__global__ __launch_bounds__(256) void prep_csr_kernel(
    const float* __restrict__ A, const float* __restrict__ X,
    const float* __restrict__ W, int* __restrict__ deg,
    u16* __restrict__ lists, u16* __restrict__ Xb, u16* __restrict__ WT)
{
    __shared__ u16 sT[16][520];            // 16.6 KB; csr aliases sT[0..1] as cnt
    int tid = threadIdx.x;
    int b   = blockIdx.x;

    if (b < 1024) {
        size_t idx = ((size_t)b * 256 + tid) * 8;
        float4 v0 = *(const float4*)(X + idx);
        float4 v1 = *(const float4*)(X + idx + 4);
        u16 o[8] = {f2u16(v0.x), f2u16(v0.y), f2u16(v0.z), f2u16(v0.w),
                    f2u16(v1.x), f2u16(v1.y), f2u16(v1.z), f2u16(v1.w)};
        *(bf16x8*)(Xb + idx) = *(bf16x8*)o;
        return;
    }
    if (b < 1088) {
        int wb = b - 1024;                 // 0..63
        int h  = wb >> 3;
        int s16 = (wb & 7) * 16;
        const float* Wh = W + (size_t)h * GF * GC;
        for (int pass = 0; pass < 8; ++pass) {
            int k  = pass * 64 + (tid >> 2);
            int n4 = tid & 3;
            float4 v = *(const float4*)&Wh[(size_t)k * GC + s16 + n4 * 4];
            sT[n4 * 4 + 0][k] = f2u16(v.x);
            sT[n4 * 4 + 1][k] = f2u16(v.y);
            sT[n4 * 4 + 2][k] = f2u16(v.z);
            sT[n4 * 4 + 3][k] = f2u16(v.w);
        }
        __syncthreads();
        int n = tid >> 4, seg = tid & 15;
        u16* dst = WT + ((size_t)h * GC + s16 + n) * GF + seg * 32;
#pragma unroll
        for (int s = 0; s < 4; ++s)
            *(bf16x8*)(dst + s * 8) = *(const bf16x8*)&sT[n][seg * 32 + s * 8];
        return;
    }

    // ---- csr: row i ----
    int i    = b - 1088;
    int lane = tid & 63;
    int* cnt = (int*)&sT[0][0];
    if (tid == 0) *cnt = 0;
    __syncthreads();

    u16* row = lists + (size_t)i * CAP;
    const float4* Arow = (const float4*)(A + (size_t)i * GN);
    unsigned long long ltmask = (lane == 63) ? ~0ull >> 1
                                             : (1ull << lane) - 1;

    float4 av[4];                          // 4 independent loads in flight
#pragma unroll
    for (int it = 0; it < 4; ++it) av[it] = Arow[it * 256 + tid];

#pragma unroll
    for (int it = 0; it < 4; ++it) {
        float4 a = av[it];
        int j = (it * 256 + tid) * 4;
        bool f0 = a.x > 0.5f, f1 = a.y > 0.5f, f2 = a.z > 0.5f, f3 = a.w > 0.5f;
        unsigned long long m0 = __ballot(f0);
        unsigned long long m1 = __ballot(f1);
        unsigned long long m2 = __ballot(f2);
        unsigned long long m3 = __ballot(f3);
        int c0 = __popcll(m0), c1 = __popcll(m1), c2 = __popcll(m2);
        int tot = c0 + c1 + c2 + __popcll(m3);
        int base = 0;
        if (lane == 0 && tot) base = atomicAdd(cnt, tot);
        base = __shfl(base, 0);
        if (tot) {
            if (f0) {
                int s = base + __popcll(m0 & ltmask);
                if (s < CAP) row[s] = (u16)j;
            }
            if (f1) {
                int s = base + c0 + __popcll(m1 & ltmask);
                if (s < CAP) row[s] = (u16)(j + 1);
            }
            if (f2) {
                int s = base + c0 + c1 + __popcll(m2 & ltmask);
                if (s < CAP) row[s] = (u16)(j + 2);
            }
            if (f3) {
                int s = base + c0 + c1 + c2 + __popcll(m3 & ltmask);
                if (s < CAP) row[s] = (u16)(j + 3);
            }
        }
    }
    __syncthreads();
    if (tid == 0) deg[i] = *cnt < CAP ? *cnt : CAP;
}

// ---------------------------------------------------------------------------
// Kernel 2 (MFMA feats — r4 body): feats = Xb @ WT^T, BM=64 BN=128 BK=64.
// Output layout [hp][N][2*C] (2 MB head-pair slabs, attn L2 phasing).
// Direct bf16 epilogue stores.
// ---------------------------------------------------------------------------
__global__ __launch_bounds__(256) void feats_kernel(
    const u16* __restrict__ Xb, const u16* __restrict__ WT,
    const float* __restrict__ a_self, const float* __restrict__ a_neigh,
    u16* __restrict__ featsb, float* __restrict__ ssT,
    float* __restrict__ snT)
{
    __shared__ u16 sX[64 * XS];    //  9.2 KB
    __shared__ u16 sW[128 * XS];   // 18.4 KB

    int h   = blockIdx.x >> 6;
    int n0  = (blockIdx.x & 63) << 6;
    int tid = threadIdx.x;
    int lane = tid & 63, wv = tid >> 6;
    int lm = lane & 15, q = lane >> 4;

    const u16* Xp = Xb + (size_t)n0 * GF;
    const u16* Wp = WT + (size_t)h * GC * GF;

    uint4 xr[2], wr[4];

#define ISSUE_TILE(K0)                                                        \
    {                                                                         \
        _Pragma("unroll")                                                     \
        for (int it = 0; it < 2; ++it) {                                      \
            int idx = it * 256 + tid, row = idx >> 3, c = idx & 7;            \
            xr[it] = *(const uint4*)&Xp[(size_t)row * GF + (K0) + c * 8];     \
        }                                                                     \
        _Pragma("unroll")                                                     \
        for (int it = 0; it < 4; ++it) {                                      \
            int idx = it * 256 + tid, row = idx >> 3, c = idx & 7;            \
            wr[it] = *(const uint4*)&Wp[(size_t)row * GF + (K0) + c * 8];     \
        }                                                                     \
    }

#define STORE_TILE()                                                          \
    {                                                                         \
        _Pragma("unroll")                                                     \
        for (int it = 0; it < 2; ++it) {                                      \
            int idx = it * 256 + tid, row = idx >> 3, c = idx & 7;            \
            *(uint4*)&sX[row * XS + c * 8] = xr[it];                          \
        }                                                                     \
        _Pragma("unroll")                                                     \
        for (int it = 0; it < 4; ++it) {                                      \
            int idx = it * 256 + tid, row = idx >> 3, c = idx & 7;            \
            *(uint4*)&sW[row * XS + c * 8] = wr[it];                          \
        }                                                                     \
    }

    f32x4 acc[8];
#pragma unroll
    for (int nt = 0; nt < 8; ++nt) acc[nt] = (f32x4){0.f, 0.f, 0.f, 0.f};

    ISSUE_TILE(0)
    STORE_TILE()

    for (int k0 = 0; k0 < GF; k0 += 64) {
        __syncthreads();                       // tile k0 visible
        if (k0 + 64 < GF) ISSUE_TILE(k0 + 64)  // next tile in flight

#pragma unroll
        for (int ks = 0; ks < 64; ks += 32) {
            bf16x8 af = *(const bf16x8*)&sX[(wv * 16 + lm) * XS + ks + q * 8];
            bf16x8 bfr[8];
#pragma unroll
            for (int nt = 0; nt < 8; ++nt)
                bfr[nt] = *(const bf16x8*)&sW[(nt * 16 + lm) * XS + ks + q * 8];
#pragma unroll
            for (int nt = 0; nt < 8; ++nt)
                acc[nt] = __builtin_amdgcn_mfma_f32_16x16x32_bf16(
                    af, bfr[nt], acc[nt], 0, 0, 0);
        }
        __syncthreads();                       // readers done
        if (k0 + 64 < GF) STORE_TILE()
    }
#undef ISSUE_TILE
#undef STORE_TILE

    // epilogue: direct bf16 stores into [hp][N][2C] + fused score vectors
    float aS[8], aN[8];
#pragma unroll
    for (int nt = 0; nt < 8; ++nt) {
        aS[nt] = a_self[h * GC + nt * 16 + lm];
        aN[nt] = a_neigh[h * GC + nt * 16 + lm];
    }
    float vs[4] = {0.f, 0.f, 0.f, 0.f};
    float vn[4] = {0.f, 0.f, 0.f, 0.f};
    int rbase = n0 + wv * 16 + q * 4;          // D row = quad*4+reg (m89)
    u16* fB = featsb + (size_t)(h >> 1) * GN * 256 + (h & 1) * 128;
#pragma unroll
    for (int nt = 0; nt < 8; ++nt) {
        f32x4 v = acc[nt];
        int col = nt * 16 + lm;                // D col = lane&15
#pragma unroll
        for (int r = 0; r < 4; ++r) {
            fB[(size_t)(rbase + r) * 256 + col] = f2u16(v[r]);
            vs[r] += v[r] * aS[nt];
            vn[r] += v[r] * aN[nt];
        }
    }
#pragma unroll
    for (int r = 0; r < 4; ++r) {
        for (int off = 1; off < 16; off <<= 1) {
            vs[r] += __shfl_xor(vs[r], off);
            vn[r] += __shfl_xor(vn[r], off);
        }
        if (lm == 0) {
            ssT[(rbase + r) * GH + h] = vs[r];
            snT[(rbase + r) * GH + h] = vn[r];
        }
    }
}

// ---------------------------------------------------------------------------
// Kernel 3 (attn — r7 body): XCD-affine slab pinning + register softmax
// (single LDS write) + parity-split dwordx4 gather, 4-pair unroll.
// ---------------------------------------------------------------------------
__global__ __launch_bounds__(256) void attn_kernel(
    const int* __restrict__ deg, const u16* __restrict__ lists,
    const float* __restrict__ bias, const u16* __restrict__ featsb,
    const float* __restrict__ ssT, const float* __restrict__ snT,
    float* __restrict__ out)
{
    int tid  = threadIdx.x;
    int wv   = tid >> 6, lane = tid & 63;
    int bid  = blockIdx.x;
    int r8   = bid & 7;                    // presumed XCD id
    int hp   = r8 >> 1;                    // slab pinned to XCD pair
    int i    = (bid >> 3) * 8 + (r8 & 1) * 4 + wv;   // 0..4095, bijective

    __shared__ float4 pjbuf[4][LCAP];      // 8 KB: (p0, p1, j, pad) per wave
    float4* pj = pjbuf[wv];

    int M = deg[i];
    M = M < LCAP ? M : LCAP;
    const u16* row = lists + (size_t)i * CAP;

    float2 ssv = *(const float2*)&ssT[(size_t)i * GH + hp * 2];

    // single pass: scores for this lane's <=2 neighbors stay in registers
    int ka = lane, kb = lane + 64;
    int ja = 0, jb = 0;
    float e0a = -1e30f, e1a = -1e30f, e0b = -1e30f, e1b = -1e30f;
    if (ka < M) {
        ja = row[ka];
        float2 sn = *(const float2*)&snT[(size_t)ja * GH + hp * 2];
        e0a = ssv.x + sn.x; e0a = e0a > 0.f ? e0a : 0.2f * e0a;
        e1a = ssv.y + sn.y; e1a = e1a > 0.f ? e1a : 0.2f * e1a;
    }
    if (kb < M) {
        jb = row[kb];
        float2 sn = *(const float2*)&snT[(size_t)jb * GH + hp * 2];
        e0b = ssv.x + sn.x; e0b = e0b > 0.f ? e0b : 0.2f * e0b;
        e1b = ssv.y + sn.y; e1b = e1b > 0.f ? e1b : 0.2f * e1b;
    }
    float m0 = fmaxf(e0a, e0b), m1 = fmaxf(e1a, e1b);
#pragma unroll
    for (int off = 32; off > 0; off >>= 1) {
        m0 = fmaxf(m0, __shfl_xor(m0, off));
        m1 = fmaxf(m1, __shfl_xor(m1, off));
    }

    // exp from registers, one LDS write, sums
    float s0 = 0.f, s1 = 0.f;
    if (ka < M) {
        float p0 = __expf(e0a - m0), p1 = __expf(e1a - m1);
        pj[ka] = make_float4(p0, p1, __int_as_float(ja), 0.f);
        s0 += p0; s1 += p1;
    }
    if (kb < M) {
        float p0 = __expf(e0b - m0), p1 = __expf(e1b - m1);
        pj[kb] = make_float4(p0, p1, __int_as_float(jb), 0.f);
        s0 += p0; s1 += p1;
    }
#pragma unroll
    for (int off = 32; off > 0; off >>= 1) {
        s0 += __shfl_xor(s0, off);
        s1 += __shfl_xor(s1, off);
    }

    int par = lane >> 5;                   // neighbor-parity of this lane
    int cl  = lane & 31;                   // 16 B channel block 0..31
    float inv = (cl < 16) ? 1.f / s0 : 1.f / s1;

    // gather: lane reads 16 B (8 channels) of neighbor (k + par)'s 512 B row
    const u16* fb = featsb + (size_t)hp * GN * 256 + cl * 8;
    float a0 = 0.f, a1 = 0.f, a2 = 0.f, a3 = 0.f;
    float a4 = 0.f, a5 = 0.f, a6 = 0.f, a7 = 0.f;

#define ACCUM(Q, WW)                                                          \
    {                                                                         \
        a0 += (WW) * bf2f((Q)[0]); a1 += (WW) * bf2f((Q)[1]);                 \
        a2 += (WW) * bf2f((Q)[2]); a3 += (WW) * bf2f((Q)[3]);                 \
        a4 += (WW) * bf2f((Q)[4]); a5 += (WW) * bf2f((Q)[5]);                 \
        a6 += (WW) * bf2f((Q)[6]); a7 += (WW) * bf2f((Q)[7]);                 \
    }

    int k = 0;
    for (; k + 8 <= M; k += 8) {           // 4 pairs = 4 loads in flight
        float4 v0 = pj[k + par];           // 2-way broadcast (free)
        float4 v1 = pj[k + 2 + par];
        float4 v2 = pj[k + 4 + par];
        float4 v3 = pj[k + 6 + par];
        int j0 = __float_as_int(v0.z), j1 = __float_as_int(v1.z);
        int j2 = __float_as_int(v2.z), j3 = __float_as_int(v3.z);
        bf16x8 q0 = *(const bf16x8*)(fb + (size_t)j0 * 256);
        bf16x8 q1 = *(const bf16x8*)(fb + (size_t)j1 * 256);
        bf16x8 q2 = *(const bf16x8*)(fb + (size_t)j2 * 256);
        bf16x8 q3 = *(const bf16x8*)(fb + (size_t)j3 * 256);
        float w0 = (cl < 16) ? v0.x : v0.y;
        float w1 = (cl < 16) ? v1.x : v1.y;
        float w2 = (cl < 16) ? v2.x : v2.y;
        float w3 = (cl < 16) ? v3.x : v3.y;
        ACCUM(q0, w0)
        ACCUM(q1, w1)
        ACCUM(q2, w2)
        ACCUM(q3, w3)
    }
    if (k + 4 <= M) {
        float4 v0 = pj[k + par], v1 = pj[k + 2 + par];
        int j0 = __float_as_int(v0.z), j1 = __float_as_int(v1.z);
        bf16x8 q0 = *(const bf16x8*)(fb + (size_t)j0 * 256);
        bf16x8 q1 = *(const bf16x8*)(fb + (size_t)j1 * 256);
        float w0 = (cl < 16) ? v0.x : v0.y;
        float w1 = (cl < 16) ? v1.x : v1.y;
        ACCUM(q0, w0)
        ACCUM(q1, w1)
        k += 4;
    }
    if (k + 2 <= M) {
        float4 v0 = pj[k + par];
        int j0 = __float_as_int(v0.z);
        bf16x8 q0 = *(const bf16x8*)(fb + (size_t)j0 * 256);
        float w0 = (cl < 16) ? v0.x : v0.y;
        ACCUM(q0, w0)
        k += 2;
    }
    if (k < M) {                           // single tail: par==1 lanes idle
        float4 v0 = pj[k];
        int j0 = __float_as_int(v0.z);
        bf16x8 q0 = *(const bf16x8*)(fb + (size_t)j0 * 256);
        float w0 = (cl < 16) ? v0.x : v0.y;
        if (par) w0 = 0.f;
        ACCUM(q0, w0)
    }
#undef ACCUM

    // merge parity partial sums (lane l <-> l+32 hold same channels)
    a0 += __shfl_xor(a0, 32); a1 += __shfl_xor(a1, 32);
    a2 += __shfl_xor(a2, 32); a3 += __shfl_xor(a3, 32);
    a4 += __shfl_xor(a4, 32); a5 += __shfl_xor(a5, 32);
    a6 += __shfl_xor(a6, 32); a7 += __shfl_xor(a7, 32);

    if (par == 0) {
        int co = hp * 256 + cl * 8;        // channel offset in [H*C]
        float4 b0 = *(const float4*)&bias[co];
        float4 b1 = *(const float4*)&bias[co + 4];
        float* op = out + (size_t)i * (GH * GC) + co;
        float4 o0, o1;
        o0.x = fmaxf(a0 * inv + b0.x, 0.f);
        o0.y = fmaxf(a1 * inv + b0.y, 0.f);
        o0.z = fmaxf(a2 * inv + b0.z, 0.f);
        o0.w = fmaxf(a3 * inv + b0.w, 0.f);
        o1.x = fmaxf(a4 * inv + b1.x, 0.f);
        o1.y = fmaxf(a5 * inv + b1.y, 0.f);
        o1.z = fmaxf(a6 * inv + b1.z, 0.f);
        o1.w = fmaxf(a7 * inv + b1.w, 0.f);
        *(float4*)op = o0;
        *(float4*)(op + 4) = o1;
    }
}

// ---------------------------------------------------------------------------
extern "C" void kernel_launch(void* const* d_in, const int* in_sizes, int n_in,
                              void* d_out, int out_size, void* d_ws, size_t ws_size,
                              hipStream_t stream)
{
    const float* X       = (const float*)d_in[0];
    const float* A       = (const float*)d_in[1];
    const float* W       = (const float*)d_in[2];
    const float* a_self  = (const float*)d_in[3];
    const float* a_neigh = (const float*)d_in[4];
    const float* bias    = (const float*)d_in[5];
    float* out = (float*)d_out;

    // ws layout: featsb bf16 [4][N][2C] | ssT f32 [N][H] | snT f32 [N][H]
    //            | deg i32 [N] | lists u16 [N*CAP] | Xb u16 [N*F] | WT u16 [H*C*F]
    u16*   featsb = (u16*)d_ws;
    float* ssT    = (float*)(featsb + (size_t)GH * GN * GC);
    float* snT    = ssT + (size_t)GH * GN;
    int*   deg    = (int*)(snT + (size_t)GH * GN);
    u16*   lists  = (u16*)(deg + GN);
    u16*   Xb     = lists + (size_t)GN * CAP;
    u16*   WT     = Xb + (size_t)GN * GF;

    prep_csr_kernel<<<1088 + GN, 256, 0, stream>>>(A, X, W, deg, lists, Xb, WT);
    feats_kernel<<<GH * 64, 256, 0, stream>>>(Xb, WT, a_self, a_neigh,
                                              featsb, ssT, snT);
    attn_kernel<<<GH * GN / 8, 256, 0, stream>>>(deg, lists, bias, featsb,
                                                 ssT, snT, out);
}